// Round 23
// baseline (119.709 us; speedup 1.0000x reference)
//
#include <hip/hip_runtime.h>
#include <hip/hip_bf16.h>
#include <math.h>

// ---------------------------------------------------------------------------
// GCN 2-layer forward. Pipeline (6 dispatches, ZERO global atomics):
//   1) histgemm: hist blocks FIRST (98 chunks x 2 halves, 8-bit packed 25KB
//      LDS histogram -> rank8[i], cw[c][word]); GEMM1 blocks backfill
//      (MFMA, 2-pass bf16(x)*(Wh+Wl), W split from fp32 W1 inline)
//   2) chpfx: parallel packed per-chunk prefix; count[d]; bsum
//   3) scan2 -> rd2 = {row_start, dinv}; seeds self-loop edata (4B packed)
//   4) fill: direct scatter edata[slot] = src | bf16(norm)<<16  (4B)
//   5) MEGA-B: agg1 (x16-deep gather MLP, 4B edata) -> h in LDS -> gemm2
//   6) AGG2 (bf16 h2, 8 lanes/node, x16 unroll, 4B edata) + log_softmax
// ---------------------------------------------------------------------------

#define FIN 256
#define FH  128
#define FO  16
#define ECH_LOG 13          // 8192 edges per chunk
#define ECH (1 << ECH_LOG)
#define NCHUNK 98           // ceil(800000 / 8192)
#define WPH 6272            // words per half (guard-padded >= 6250)

typedef unsigned int uint;
typedef unsigned short ushort;
typedef unsigned char uchar;
typedef __attribute__((ext_vector_type(8))) short bf16x8;
typedef __attribute__((ext_vector_type(4))) float f32x4;

static __device__ __forceinline__ ushort f2bf(float f) {
    __hip_bfloat16 b = __float2bfloat16(f);
    return *reinterpret_cast<ushort*>(&b);
}
static __device__ __forceinline__ float bf2f(ushort u) {
    return __uint_as_float(((uint)u) << 16);
}

// GEMM1 tile params
#define G1_BR 64
#define G1_KC 32

// blocks [0, nHist): hist (c = bid>>1, half = bid&1); [nHist, +nGemm): GEMM1.
// hist: 8-bit packed LDS histogram (4 nodes/word); rank8[i] = byte rank.
// GEMM1: h1(bf16)[N][128] = bf16(x) @ (Wh + Wl), 2-pass MFMA, KC=32.
//        W split hi/lo computed inline from fp32 W1 (L2-resident).
__global__ __launch_bounds__(256, 4) void GCN_histgemm_k(
        const float* __restrict__ x, const float* __restrict__ W1,
        ushort* __restrict__ h1,
        const int* __restrict__ edge, uint* __restrict__ cw,
        uchar* __restrict__ rank8,
        int N, int E, int nHist, int nWords, int wph) {
    __shared__ __align__(16) char smem[WPH * 4];   // 25088 B
    int tid = threadIdx.x;

    if ((int)blockIdx.x < nHist) {
        // ---- hist path ----
        int bid = blockIdx.x;
        int half = bid & 1;
        int c = bid >> 1;
        uint* lh = (uint*)smem;
        int w0 = half * wph;
        int wlim = nWords - w0; if (wlim > wph) wlim = wph;
        for (int j = tid; j < wlim; j += 256) lh[j] = 0;
        __syncthreads();
        int base = c << ECH_LOG;
        int lim = base + ECH; if (lim > E) lim = E;
        for (int i = base + tid; i < lim; i += 256) {
            int d = edge[E + i];
            int wd = (d >> 2) - w0;
            if ((unsigned)wd < (unsigned)wlim) {
                int sh = (d & 3) << 3;
                uint old = atomicAdd(&lh[wd], 1u << sh);
                rank8[i] = (uchar)((old >> sh) & 0xFFu);
            }
        }
        __syncthreads();
        for (int j = tid; j < wlim; j += 256)
            cw[(size_t)c * nWords + w0 + j] = lh[j];
        return;
    }

    // ---- gemm1 path (2-pass: xh*(wh+wl), W split inline) ----
    ushort* xh_s = (ushort*)smem;              // 4 KiB
    ushort* wh_s = (ushort*)(smem + 4096);     // 8 KiB
    ushort* wl_s = (ushort*)(smem + 12288);    // 8 KiB
    int row0 = (blockIdx.x - nHist) * G1_BR;
    int ln = tid & 63;
    int w  = tid >> 6;          // wave 0..3 -> col slab w*32
    int ln15 = ln & 15;
    int q16  = ln >> 4;         // k-slot 0..3

    f32x4 acc[4][2];
    #pragma unroll
    for (int mr = 0; mr < 4; mr++)
        #pragma unroll
        for (int nc = 0; nc < 2; nc++) acc[mr][nc] = (f32x4){0.f, 0.f, 0.f, 0.f};

    for (int kc = 0; kc < FIN; kc += G1_KC) {
        // stage x tile [64r][32k] as bf16
        #pragma unroll
        for (int j = 0; j < 2; j++) {
            int u = tid + j * 256;
            int r = u >> 3, kq = u & 7;       // 8 float4 per row
            int gr = row0 + r;
            float4 v = make_float4(0.f, 0.f, 0.f, 0.f);
            if (gr < N) v = *(const float4*)&x[(size_t)gr * FIN + kc + kq * 4];
            uint2 hw;
            hw.x = (uint)f2bf(v.x) | ((uint)f2bf(v.y) << 16);
            hw.y = (uint)f2bf(v.z) | ((uint)f2bf(v.w) << 16);
            int byte = (r * 64 + kq * 8) ^ (((r >> 1) & 3) << 4);
            *(uint2*)((char*)xh_s + byte) = hw;
        }
        // stage W tile [128c][32k] hi/lo from fp32 W1 (transpose in regs)
        #pragma unroll
        for (int j = 0; j < 4; j++) {
            int u = tid + j * 256;            // 0..1023
            int col = u & 127;
            int k4 = (u >> 7) * 4;            // 0,4,...,28
            ushort hh[4], hl[4];
            #pragma unroll
            for (int t = 0; t < 4; t++) {
                float v = W1[(size_t)(kc + k4 + t) * FH + col];
                hh[t] = f2bf(v);
                hl[t] = f2bf(v - bf2f(hh[t]));
            }
            uint2 hv, lv;
            hv.x = (uint)hh[0] | ((uint)hh[1] << 16);
            hv.y = (uint)hh[2] | ((uint)hh[3] << 16);
            lv.x = (uint)hl[0] | ((uint)hl[1] << 16);
            lv.y = (uint)hl[2] | ((uint)hl[3] << 16);
            int byte = (col * 64 + k4 * 2) ^ (((col >> 1) & 3) << 4);
            *(uint2*)((char*)wh_s + byte) = hv;
            *(uint2*)((char*)wl_s + byte) = lv;
        }
        __syncthreads();

        bf16x8 ah[4], bh[2], bl[2];
        #pragma unroll
        for (int mr = 0; mr < 4; mr++) {
            int r = mr * 16 + ln15;
            int byte = r * 64 + ((q16 * 16) ^ (((r >> 1) & 3) << 4));
            ah[mr] = *(const bf16x8*)((const char*)xh_s + byte);
        }
        #pragma unroll
        for (int nc = 0; nc < 2; nc++) {
            int c = w * 32 + nc * 16 + ln15;
            int byte = c * 64 + ((q16 * 16) ^ (((c >> 1) & 3) << 4));
            bh[nc] = *(const bf16x8*)((const char*)wh_s + byte);
            bl[nc] = *(const bf16x8*)((const char*)wl_s + byte);
        }
        #pragma unroll
        for (int mr = 0; mr < 4; mr++)
            #pragma unroll
            for (int nc = 0; nc < 2; nc++) {
                acc[mr][nc] = __builtin_amdgcn_mfma_f32_16x16x32_bf16(
                    ah[mr], bh[nc], acc[mr][nc], 0, 0, 0);
                acc[mr][nc] = __builtin_amdgcn_mfma_f32_16x16x32_bf16(
                    ah[mr], bl[nc], acc[mr][nc], 0, 0, 0);
            }
        __syncthreads();
    }

    // epilogue: D layout col=lane&15, row=(lane>>4)*4+reg  [m89-verified]
    #pragma unroll
    for (int mr = 0; mr < 4; mr++) {
        #pragma unroll
        for (int nc = 0; nc < 2; nc++) {
            int cw2 = w * 32 + nc * 16 + ln15;
            #pragma unroll
            for (int j = 0; j < 4; j++) {
                int gr = row0 + mr * 16 + q16 * 4 + j;
                if (gr < N) h1[(size_t)gr * FH + cw2] = f2bf(acc[mr][nc][j]);
            }
        }
    }
}

// chpfx (parallel): block = 64 words x 4 chunk-groups. Per-group partial
// byte-lane sums -> LDS -> per-group base -> in-place packed prefix rewrite.
__global__ __launch_bounds__(256) void GCN_chpfx_k(uint* __restrict__ cw,
                                                   int* __restrict__ count,
                                                   int* __restrict__ bsum,
                                                   int N, int nWords) {
    __shared__ int part[4][64][4];
    __shared__ int red[64];
    int tid = threadIdx.x;
    int wl = tid & 63, g = tid >> 6;
    int w = blockIdx.x * 64 + wl;
    int c0 = g * 25;
    int c1 = c0 + 25; if (c1 > NCHUNK) c1 = NCHUNK;

    int s0 = 0, s1 = 0, s2 = 0, s3 = 0;
    if (w < nWords) {
        for (int c = c0; c < c1; c++) {
            uint v = cw[(size_t)c * nWords + w];
            s0 += (int)(v & 0xFFu);
            s1 += (int)((v >> 8) & 0xFFu);
            s2 += (int)((v >> 16) & 0xFFu);
            s3 += (int)((v >> 24) & 0xFFu);
        }
    }
    part[g][wl][0] = s0; part[g][wl][1] = s1;
    part[g][wl][2] = s2; part[g][wl][3] = s3;
    __syncthreads();

    int b0 = 0, b1 = 0, b2 = 0, b3 = 0;
    for (int gg = 0; gg < g; gg++) {
        b0 += part[gg][wl][0]; b1 += part[gg][wl][1];
        b2 += part[gg][wl][2]; b3 += part[gg][wl][3];
    }
    if (w < nWords) {
        uint r0 = (uint)b0, r1 = (uint)b1, r2 = (uint)b2, r3 = (uint)b3;
        for (int c = c0; c < c1; c++) {
            uint* p = &cw[(size_t)c * nWords + w];
            uint v = *p;
            *p = (r0 & 0xFFu) | ((r1 & 0xFFu) << 8) | ((r2 & 0xFFu) << 16) | ((r3 & 0xFFu) << 24);
            r0 += v & 0xFFu;
            r1 += (v >> 8) & 0xFFu;
            r2 += (v >> 16) & 0xFFu;
            r3 += (v >> 24) & 0xFFu;
        }
    }
    int local = 0;
    if (g == 3 && w < nWords) {
        int t0 = b0 + s0, t1 = b1 + s1, t2 = b2 + s2, t3 = b3 + s3;
        int d0 = 4 * w;
        if (d0 + 0 < N) count[d0 + 0] = t0;
        if (d0 + 1 < N) count[d0 + 1] = t1;
        if (d0 + 2 < N) count[d0 + 2] = t2;
        if (d0 + 3 < N) count[d0 + 3] = t3;
        local = t0 + t1 + t2 + t3 + 4;
    }
    if (g == 3) red[wl] = local;
    __syncthreads();
    if (tid < 32) { red[tid] += red[tid + 32]; }
    __syncthreads();
    if (tid < 16) { red[tid] += red[tid + 16]; }
    __syncthreads();
    if (tid < 8) { red[tid] += red[tid + 8]; }
    __syncthreads();
    if (tid < 4) { red[tid] += red[tid + 4]; }
    __syncthreads();
    if (tid == 0) bsum[blockIdx.x] = red[0] + red[1] + red[2] + red[3];
}

// scan2: 1 node/thread. rd2[v] = {row_start[v], bits(dinv[v])}; rd2[N].x =
// total; seeds self-loop entry edata[row_start[v]] = v | bf16(dinv^2)<<16.
__global__ __launch_bounds__(256) void GCN_scan2_k(const int* __restrict__ count,
                                                   const int* __restrict__ bsum,
                                                   int2* __restrict__ rd2,
                                                   uint* __restrict__ edata, int N) {
    int tid = threadIdx.x;
    int b = blockIdx.x;
    int d = b * 256 + tid;
    int cnt1 = (d < N) ? count[d] + 1 : 0;

    __shared__ int red[256];
    int offp = 0;
    for (int t = tid; t < b; t += 256) offp += bsum[t];
    red[tid] = offp;
    __syncthreads();
    for (int st = 128; st > 0; st >>= 1) {
        if (tid < st) red[tid] += red[tid + st];
        __syncthreads();
    }
    int blockOff = red[0];
    __syncthreads();

    __shared__ int ssum[256];
    ssum[tid] = cnt1;
    __syncthreads();
    for (int off = 1; off < 256; off <<= 1) {
        int t = (tid >= off) ? ssum[tid - off] : 0;
        __syncthreads();
        ssum[tid] += t;
        __syncthreads();
    }
    int r = blockOff + ssum[tid] - cnt1;   // exclusive

    if (d < N) {
        float dv = rsqrtf((float)cnt1);
        rd2[d] = make_int2(r, __float_as_int(dv));
        edata[r] = (uint)d | ((uint)f2bf(dv * dv) << 16);   // self-loop
    }
    if (b == gridDim.x - 1 && tid == 255) rd2[N] = make_int2(blockOff + ssum[255], 0);
}

// fill: direct scatter, no atomics.
// slot = rs[d]+1+byte(cw[c][d>>2],d&3)+rank8[i], c = i>>13;
// edata[slot] = src | bf16(norm)<<16  (4B packed).
__global__ __launch_bounds__(256) void GCN_fill_k(const int* __restrict__ edge,
                                                  const uchar* __restrict__ rank8,
                                                  const uint* __restrict__ cw,
                                                  const int2* __restrict__ rd2,
                                                  uint* __restrict__ edata,
                                                  int E, int nWords) {
    int i = blockIdx.x * 256 + threadIdx.x;
    if (i >= E) return;
    int s = edge[i];
    int d = edge[E + i];
    int rk = (int)rank8[i];
    int c = i >> ECH_LOG;
    uint pw = cw[(size_t)c * nWords + (d >> 2)];
    int pfx = (int)((pw >> ((d & 3) << 3)) & 0xFFu);
    int2 rdd = rd2[d];
    float ds = __int_as_float(rd2[s].y);
    float nr = ds * __int_as_float(rdd.y);
    edata[rdd.x + 1 + pfx + rk] = (uint)s | ((uint)f2bf(nr) << 16);
}

// MEGA-B: agg1 (16 lanes/node, x16-deep gather MLP) -> h in LDS -> gemm2.
// edata packed 4B: src = lo16, norm = bf16 hi16. h2 written bf16.
__global__ __launch_bounds__(256) void GCN_agg1gemm2_k(
        const ushort* __restrict__ h1, const int2* __restrict__ rd2,
        const uint* __restrict__ ed, const float* __restrict__ b1,
        const float* __restrict__ W2, ushort* __restrict__ h2b, int N) {
    __shared__ float w2s[FH][FO];        // 8 KiB
    __shared__ float hs[16][FH + 4];     // 8.25 KiB
    int tid = threadIdx.x;
    #pragma unroll
    for (int j = 0; j < (FH * FO) / 256; j++) {
        int i = tid + j * 256;
        w2s[i >> 4][i & 15] = W2[i];
    }

    int node0 = blockIdx.x * 16;
    int local = tid >> 4;
    int j = tid & 15;             // 16B unit: cols 8j..8j+7
    int node = node0 + local;

    if (node < N) {
        int beg = rd2[node].x, end = rd2[node + 1].x;
        const uint4* hp = (const uint4*)h1;

        float a[8];
        #pragma unroll
        for (int t = 0; t < 8; t++) a[t] = 0.f;

        int i = beg;
        for (; i + 16 <= end; i += 16) {
            uint e[16];
            uint4 gg[16];
            #pragma unroll
            for (int t = 0; t < 16; t++) e[t] = ed[i + t];
            #pragma unroll
            for (int t = 0; t < 16; t++) gg[t] = hp[(size_t)(e[t] & 0xFFFFu) * 16 + j];
            #pragma unroll
            for (int t = 0; t < 16; t++) {
                float w = bf2f((ushort)(e[t] >> 16));
                #pragma unroll
                for (int q = 0; q < 4; q++) {
                    uint u = (&gg[t].x)[q];
                    a[q*2+0] += __uint_as_float(u << 16) * w;
                    a[q*2+1] += __uint_as_float(u & 0xFFFF0000u) * w;
                }
            }
        }
        for (; i + 8 <= end; i += 8) {
            uint e[8];
            uint4 gg[8];
            #pragma unroll
            for (int t = 0; t < 8; t++) e[t] = ed[i + t];
            #pragma unroll
            for (int t = 0; t < 8; t++) gg[t] = hp[(size_t)(e[t] & 0xFFFFu) * 16 + j];
            #pragma unroll
            for (int t = 0; t < 8; t++) {
                float w = bf2f((ushort)(e[t] >> 16));
                #pragma unroll
                for (int q = 0; q < 4; q++) {
                    uint u = (&gg[t].x)[q];
                    a[q*2+0] += __uint_as_float(u << 16) * w;
                    a[q*2+1] += __uint_as_float(u & 0xFFFF0000u) * w;
                }
            }
        }
        for (; i < end; i++) {
            uint e = ed[i];
            float w = bf2f((ushort)(e >> 16));
            uint4 g = hp[(size_t)(e & 0xFFFFu) * 16 + j];
            #pragma unroll
            for (int q = 0; q < 4; q++) {
                uint u = (&g.x)[q];
                a[q*2+0] += __uint_as_float(u << 16) * w;
                a[q*2+1] += __uint_as_float(u & 0xFFFF0000u) * w;
            }
        }

        const float4* bp = (const float4*)b1;
        float4 bb0 = bp[j * 2 + 0];
        float4 bb1 = bp[j * 2 + 1];
        float4 o0, o1;
        o0.x = fmaxf(a[0] + bb0.x, 0.f);
        o0.y = fmaxf(a[1] + bb0.y, 0.f);
        o0.z = fmaxf(a[2] + bb0.z, 0.f);
        o0.w = fmaxf(a[3] + bb0.w, 0.f);
        o1.x = fmaxf(a[4] + bb1.x, 0.f);
        o1.y = fmaxf(a[5] + bb1.y, 0.f);
        o1.z = fmaxf(a[6] + bb1.z, 0.f);
        o1.w = fmaxf(a[7] + bb1.w, 0.f);
        *(float4*)&hs[local][j * 8 + 0] = o0;
        *(float4*)&hs[local][j * 8 + 4] = o1;
    }
    __syncthreads();

    float acc = 0.f;
    #pragma unroll 8
    for (int k = 0; k < FH; k++) acc += hs[local][k] * w2s[k][j];
    if (node < N) h2b[(size_t)node * FO + j] = f2bf(acc);
}

// AGG2 (bf16 h2, 4B edata) + bias + log_softmax. 8 lanes/node, x16 unroll.
__global__ __launch_bounds__(256) void GCN_agg2_k(const ushort* __restrict__ h2b,
                                                  const int2* __restrict__ rd2,
                                                  const uint* __restrict__ ed,
                                                  const float* __restrict__ b2,
                                                  float* __restrict__ out, int N) {
    int tid = threadIdx.x;
    int node = blockIdx.x * 32 + (tid >> 3);
    if (node >= N) return;
    int f2 = tid & 7;                        // cols 2*f2, 2*f2+1
    int beg = rd2[node].x, end = rd2[node + 1].x;
    const uint* hp = (const uint*)h2b;       // row = 8 uints (16 bf16)
    float a0 = 0.f, a1 = 0.f;
    int i = beg;
    for (; i + 16 <= end; i += 16) {
        uint e[16];
        uint u[16];
        #pragma unroll
        for (int t = 0; t < 16; t++) e[t] = ed[i + t];
        #pragma unroll
        for (int t = 0; t < 16; t++) u[t] = hp[(size_t)(e[t] & 0xFFFFu) * 8 + f2];
        #pragma unroll
        for (int t = 0; t < 16; t++) {
            float w = bf2f((ushort)(e[t] >> 16));
            a0 += __uint_as_float(u[t] << 16) * w;
            a1 += __uint_as_float(u[t] & 0xFFFF0000u) * w;
        }
    }
    for (; i + 8 <= end; i += 8) {
        uint e[8];
        uint u[8];
        #pragma unroll
        for (int t = 0; t < 8; t++) e[t] = ed[i + t];
        #pragma unroll
        for (int t = 0; t < 8; t++) u[t] = hp[(size_t)(e[t] & 0xFFFFu) * 8 + f2];
        #pragma unroll
        for (int t = 0; t < 8; t++) {
            float w = bf2f((ushort)(e[t] >> 16));
            a0 += __uint_as_float(u[t] << 16) * w;
            a1 += __uint_as_float(u[t] & 0xFFFF0000u) * w;
        }
    }
    for (; i < end; i++) {
        uint e = ed[i];
        uint u = hp[(size_t)(e & 0xFFFFu) * 8 + f2];
        float w = bf2f((ushort)(e >> 16));
        a0 += __uint_as_float(u << 16) * w;
        a1 += __uint_as_float(u & 0xFFFF0000u) * w;
    }
    float2 bb = ((const float2*)b2)[f2];
    float v0 = a0 + bb.x;
    float v1 = a1 + bb.y;
    float mx = fmaxf(v0, v1);
    #pragma unroll
    for (int m = 4; m >= 1; m >>= 1) mx = fmaxf(mx, __shfl_xor(mx, m, 8));
    float s = expf(v0 - mx) + expf(v1 - mx);
    #pragma unroll
    for (int m = 4; m >= 1; m >>= 1) s += __shfl_xor(s, m, 8);
    float ls = logf(s);
    float2 o = make_float2(v0 - mx - ls, v1 - mx - ls);
    ((float2*)out)[(size_t)node * 8 + f2] = o;
}

extern "C" void kernel_launch(void* const* d_in, const int* in_sizes, int n_in,
                              void* d_out, int out_size, void* d_ws, size_t ws_size,
                              hipStream_t stream) {
    (void)n_in; (void)out_size; (void)ws_size;
    const float* x  = (const float*)d_in[0];
    const int*   edp = (const int*)d_in[1];
    const float* W1 = (const float*)d_in[2];
    const float* b1 = (const float*)d_in[3];
    const float* W2 = (const float*)d_in[4];
    const float* b2 = (const float*)d_in[5];
    float* out = (float*)d_out;

    int N = in_sizes[0] / FIN;   // 50000
    int E = in_sizes[1] / 2;     // 800000
    int M = E + N;
    int nWords = (N + 3) / 4;                // 12500 (4 nodes/word)
    int wph = (nWords + 1) / 2;              // 6250 (<= WPH)
    int nScanBlocks = (N + 255) / 256;       // 196
    int nChpfx = (nWords + 63) / 64;         // 196

    char* p = (char*)d_ws;
    auto take = [&](size_t bytes) -> char* {
        char* r = p;
        p += (bytes + 255) & ~(size_t)255;
        return r;
    };
    int*    count  = (int*)take((size_t)N * 4);
    uchar*  rank8  = (uchar*)take((size_t)E);
    uint*   cw     = (uint*)take((size_t)NCHUNK * nWords * 4);   // 4.9 MB
    int2*   rd2    = (int2*)take((size_t)(N + 1) * 8);
    int*    bsum   = (int*)take((size_t)nChpfx * 4);
    uint*   edata  = (uint*)take((size_t)M * 4);
    ushort* h1     = (ushort*)take((size_t)N * FH * 2);
    ushort* h2b    = (ushort*)take((size_t)N * FO * 2);

    int eBlocks = (E + 255) / 256;            // 3125
    int nGemm   = (N + G1_BR - 1) / G1_BR;    // 782
    int nHist   = 2 * NCHUNK;                 // 196

    GCN_histgemm_k<<<nHist + nGemm, 256, 0, stream>>>(
        x, W1, h1, edp, cw, rank8, N, E, nHist, nWords, wph);
    GCN_chpfx_k<<<nChpfx, 256, 0, stream>>>(cw, count, bsum, N, nWords);
    GCN_scan2_k<<<nScanBlocks, 256, 0, stream>>>(count, bsum, rd2, edata, N);
    GCN_fill_k<<<eBlocks, 256, 0, stream>>>(edp, rank8, cw, rd2, edata, E, nWords);
    GCN_agg1gemm2_k<<<(N + 15) / 16, 256, 0, stream>>>(h1, rd2, edata, b1, W2, h2b, N);
    GCN_agg2_k<<<(N + 31) / 32, 256, 0, stream>>>(h2b, rd2, edata, b2, out, N);
}

// Round 24
// 108.080 us; speedup vs baseline: 1.1076x; 1.1076x over previous
//
#include <hip/hip_runtime.h>
#include <hip/hip_bf16.h>
#include <math.h>

// ---------------------------------------------------------------------------
// GCN 2-layer forward. Pipeline (6 dispatches, ZERO global atomics):
//   1) histgemm: hist blocks FIRST (98 chunks x 2 halves, 8-bit packed 25KB
//      LDS histogram -> rank8[i], cw[c][word]); GEMM1 blocks backfill
//      (MFMA, 2-pass bf16(x)*(Wh+Wl), W split from fp32 W1 inline)
//   2) chpfx: parallel packed per-chunk prefix; count[d]; bsum
//   3) scan2 -> rd2 = {row_start, dinv}; seeds self-loop edata (4B packed)
//   4) fill: direct scatter edata[slot] = src | bf16(norm)<<16  (4B)
//   5) MEGA-B: agg1 (x8-deep gather MLP, 4B edata) -> h in LDS -> gemm2
//   6) AGG2 (bf16 h2, 8 lanes/node, x8 unroll, 4B edata) + log_softmax
// ---------------------------------------------------------------------------

#define FIN 256
#define FH  128
#define FO  16
#define ECH_LOG 13          // 8192 edges per chunk
#define ECH (1 << ECH_LOG)
#define NCHUNK 98           // ceil(800000 / 8192)
#define WPH 6272            // words per half (guard-padded >= 6250)

typedef unsigned int uint;
typedef unsigned short ushort;
typedef unsigned char uchar;
typedef __attribute__((ext_vector_type(8))) short bf16x8;
typedef __attribute__((ext_vector_type(4))) float f32x4;

static __device__ __forceinline__ ushort f2bf(float f) {
    __hip_bfloat16 b = __float2bfloat16(f);
    return *reinterpret_cast<ushort*>(&b);
}
static __device__ __forceinline__ float bf2f(ushort u) {
    return __uint_as_float(((uint)u) << 16);
}

// GEMM1 tile params
#define G1_BR 64
#define G1_KC 32

// blocks [0, nHist): hist (c = bid>>1, half = bid&1); [nHist, +nGemm): GEMM1.
// hist: 8-bit packed LDS histogram (4 nodes/word); rank8[i] = byte rank.
// GEMM1: h1(bf16)[N][128] = bf16(x) @ (Wh + Wl), 2-pass MFMA, KC=32.
//        W split hi/lo computed inline from fp32 W1 (L2-resident).
__global__ __launch_bounds__(256, 4) void GCN_histgemm_k(
        const float* __restrict__ x, const float* __restrict__ W1,
        ushort* __restrict__ h1,
        const int* __restrict__ edge, uint* __restrict__ cw,
        uchar* __restrict__ rank8,
        int N, int E, int nHist, int nWords, int wph) {
    __shared__ __align__(16) char smem[WPH * 4];   // 25088 B
    int tid = threadIdx.x;

    if ((int)blockIdx.x < nHist) {
        // ---- hist path ----
        int bid = blockIdx.x;
        int half = bid & 1;
        int c = bid >> 1;
        uint* lh = (uint*)smem;
        int w0 = half * wph;
        int wlim = nWords - w0; if (wlim > wph) wlim = wph;
        for (int j = tid; j < wlim; j += 256) lh[j] = 0;
        __syncthreads();
        int base = c << ECH_LOG;
        int lim = base + ECH; if (lim > E) lim = E;
        for (int i = base + tid; i < lim; i += 256) {
            int d = edge[E + i];
            int wd = (d >> 2) - w0;
            if ((unsigned)wd < (unsigned)wlim) {
                int sh = (d & 3) << 3;
                uint old = atomicAdd(&lh[wd], 1u << sh);
                rank8[i] = (uchar)((old >> sh) & 0xFFu);
            }
        }
        __syncthreads();
        for (int j = tid; j < wlim; j += 256)
            cw[(size_t)c * nWords + w0 + j] = lh[j];
        return;
    }

    // ---- gemm1 path (2-pass: xh*(wh+wl), W split inline) ----
    ushort* xh_s = (ushort*)smem;              // 4 KiB
    ushort* wh_s = (ushort*)(smem + 4096);     // 8 KiB
    ushort* wl_s = (ushort*)(smem + 12288);    // 8 KiB
    int row0 = (blockIdx.x - nHist) * G1_BR;
    int ln = tid & 63;
    int w  = tid >> 6;          // wave 0..3 -> col slab w*32
    int ln15 = ln & 15;
    int q16  = ln >> 4;         // k-slot 0..3

    f32x4 acc[4][2];
    #pragma unroll
    for (int mr = 0; mr < 4; mr++)
        #pragma unroll
        for (int nc = 0; nc < 2; nc++) acc[mr][nc] = (f32x4){0.f, 0.f, 0.f, 0.f};

    for (int kc = 0; kc < FIN; kc += G1_KC) {
        // stage x tile [64r][32k] as bf16
        #pragma unroll
        for (int j = 0; j < 2; j++) {
            int u = tid + j * 256;
            int r = u >> 3, kq = u & 7;       // 8 float4 per row
            int gr = row0 + r;
            float4 v = make_float4(0.f, 0.f, 0.f, 0.f);
            if (gr < N) v = *(const float4*)&x[(size_t)gr * FIN + kc + kq * 4];
            uint2 hw;
            hw.x = (uint)f2bf(v.x) | ((uint)f2bf(v.y) << 16);
            hw.y = (uint)f2bf(v.z) | ((uint)f2bf(v.w) << 16);
            int byte = (r * 64 + kq * 8) ^ (((r >> 1) & 3) << 4);
            *(uint2*)((char*)xh_s + byte) = hw;
        }
        // stage W tile [128c][32k] hi/lo from fp32 W1 (transpose in regs)
        #pragma unroll
        for (int j = 0; j < 4; j++) {
            int u = tid + j * 256;            // 0..1023
            int col = u & 127;
            int k4 = (u >> 7) * 4;            // 0,4,...,28
            ushort hh[4], hl[4];
            #pragma unroll
            for (int t = 0; t < 4; t++) {
                float v = W1[(size_t)(kc + k4 + t) * FH + col];
                hh[t] = f2bf(v);
                hl[t] = f2bf(v - bf2f(hh[t]));
            }
            uint2 hv, lv;
            hv.x = (uint)hh[0] | ((uint)hh[1] << 16);
            hv.y = (uint)hh[2] | ((uint)hh[3] << 16);
            lv.x = (uint)hl[0] | ((uint)hl[1] << 16);
            lv.y = (uint)hl[2] | ((uint)hl[3] << 16);
            int byte = (col * 64 + k4 * 2) ^ (((col >> 1) & 3) << 4);
            *(uint2*)((char*)wh_s + byte) = hv;
            *(uint2*)((char*)wl_s + byte) = lv;
        }
        __syncthreads();

        bf16x8 ah[4], bh[2], bl[2];
        #pragma unroll
        for (int mr = 0; mr < 4; mr++) {
            int r = mr * 16 + ln15;
            int byte = r * 64 + ((q16 * 16) ^ (((r >> 1) & 3) << 4));
            ah[mr] = *(const bf16x8*)((const char*)xh_s + byte);
        }
        #pragma unroll
        for (int nc = 0; nc < 2; nc++) {
            int c = w * 32 + nc * 16 + ln15;
            int byte = c * 64 + ((q16 * 16) ^ (((c >> 1) & 3) << 4));
            bh[nc] = *(const bf16x8*)((const char*)wh_s + byte);
            bl[nc] = *(const bf16x8*)((const char*)wl_s + byte);
        }
        #pragma unroll
        for (int mr = 0; mr < 4; mr++)
            #pragma unroll
            for (int nc = 0; nc < 2; nc++) {
                acc[mr][nc] = __builtin_amdgcn_mfma_f32_16x16x32_bf16(
                    ah[mr], bh[nc], acc[mr][nc], 0, 0, 0);
                acc[mr][nc] = __builtin_amdgcn_mfma_f32_16x16x32_bf16(
                    ah[mr], bl[nc], acc[mr][nc], 0, 0, 0);
            }
        __syncthreads();
    }

    // epilogue: D layout col=lane&15, row=(lane>>4)*4+reg  [m89-verified]
    #pragma unroll
    for (int mr = 0; mr < 4; mr++) {
        #pragma unroll
        for (int nc = 0; nc < 2; nc++) {
            int cw2 = w * 32 + nc * 16 + ln15;
            #pragma unroll
            for (int j = 0; j < 4; j++) {
                int gr = row0 + mr * 16 + q16 * 4 + j;
                if (gr < N) h1[(size_t)gr * FH + cw2] = f2bf(acc[mr][nc][j]);
            }
        }
    }
}

// chpfx (parallel): block = 64 words x 4 chunk-groups. Per-group partial
// byte-lane sums -> LDS -> per-group base -> in-place packed prefix rewrite.
__global__ __launch_bounds__(256) void GCN_chpfx_k(uint* __restrict__ cw,
                                                   int* __restrict__ count,
                                                   int* __restrict__ bsum,
                                                   int N, int nWords) {
    __shared__ int part[4][64][4];
    __shared__ int red[64];
    int tid = threadIdx.x;
    int wl = tid & 63, g = tid >> 6;
    int w = blockIdx.x * 64 + wl;
    int c0 = g * 25;
    int c1 = c0 + 25; if (c1 > NCHUNK) c1 = NCHUNK;

    int s0 = 0, s1 = 0, s2 = 0, s3 = 0;
    if (w < nWords) {
        for (int c = c0; c < c1; c++) {
            uint v = cw[(size_t)c * nWords + w];
            s0 += (int)(v & 0xFFu);
            s1 += (int)((v >> 8) & 0xFFu);
            s2 += (int)((v >> 16) & 0xFFu);
            s3 += (int)((v >> 24) & 0xFFu);
        }
    }
    part[g][wl][0] = s0; part[g][wl][1] = s1;
    part[g][wl][2] = s2; part[g][wl][3] = s3;
    __syncthreads();

    int b0 = 0, b1 = 0, b2 = 0, b3 = 0;
    for (int gg = 0; gg < g; gg++) {
        b0 += part[gg][wl][0]; b1 += part[gg][wl][1];
        b2 += part[gg][wl][2]; b3 += part[gg][wl][3];
    }
    if (w < nWords) {
        uint r0 = (uint)b0, r1 = (uint)b1, r2 = (uint)b2, r3 = (uint)b3;
        for (int c = c0; c < c1; c++) {
            uint* p = &cw[(size_t)c * nWords + w];
            uint v = *p;
            *p = (r0 & 0xFFu) | ((r1 & 0xFFu) << 8) | ((r2 & 0xFFu) << 16) | ((r3 & 0xFFu) << 24);
            r0 += v & 0xFFu;
            r1 += (v >> 8) & 0xFFu;
            r2 += (v >> 16) & 0xFFu;
            r3 += (v >> 24) & 0xFFu;
        }
    }
    int local = 0;
    if (g == 3 && w < nWords) {
        int t0 = b0 + s0, t1 = b1 + s1, t2 = b2 + s2, t3 = b3 + s3;
        int d0 = 4 * w;
        if (d0 + 0 < N) count[d0 + 0] = t0;
        if (d0 + 1 < N) count[d0 + 1] = t1;
        if (d0 + 2 < N) count[d0 + 2] = t2;
        if (d0 + 3 < N) count[d0 + 3] = t3;
        local = t0 + t1 + t2 + t3 + 4;
    }
    if (g == 3) red[wl] = local;
    __syncthreads();
    if (tid < 32) { red[tid] += red[tid + 32]; }
    __syncthreads();
    if (tid < 16) { red[tid] += red[tid + 16]; }
    __syncthreads();
    if (tid < 8) { red[tid] += red[tid + 8]; }
    __syncthreads();
    if (tid < 4) { red[tid] += red[tid + 4]; }
    __syncthreads();
    if (tid == 0) bsum[blockIdx.x] = red[0] + red[1] + red[2] + red[3];
}

// scan2: 1 node/thread. rd2[v] = {row_start[v], bits(dinv[v])}; rd2[N].x =
// total; seeds self-loop entry edata[row_start[v]] = v | bf16(dinv^2)<<16.
__global__ __launch_bounds__(256) void GCN_scan2_k(const int* __restrict__ count,
                                                   const int* __restrict__ bsum,
                                                   int2* __restrict__ rd2,
                                                   uint* __restrict__ edata, int N) {
    int tid = threadIdx.x;
    int b = blockIdx.x;
    int d = b * 256 + tid;
    int cnt1 = (d < N) ? count[d] + 1 : 0;

    __shared__ int red[256];
    int offp = 0;
    for (int t = tid; t < b; t += 256) offp += bsum[t];
    red[tid] = offp;
    __syncthreads();
    for (int st = 128; st > 0; st >>= 1) {
        if (tid < st) red[tid] += red[tid + st];
        __syncthreads();
    }
    int blockOff = red[0];
    __syncthreads();

    __shared__ int ssum[256];
    ssum[tid] = cnt1;
    __syncthreads();
    for (int off = 1; off < 256; off <<= 1) {
        int t = (tid >= off) ? ssum[tid - off] : 0;
        __syncthreads();
        ssum[tid] += t;
        __syncthreads();
    }
    int r = blockOff + ssum[tid] - cnt1;   // exclusive

    if (d < N) {
        float dv = rsqrtf((float)cnt1);
        rd2[d] = make_int2(r, __float_as_int(dv));
        edata[r] = (uint)d | ((uint)f2bf(dv * dv) << 16);   // self-loop
    }
    if (b == gridDim.x - 1 && tid == 255) rd2[N] = make_int2(blockOff + ssum[255], 0);
}

// fill: direct scatter, no atomics.
// slot = rs[d]+1+byte(cw[c][d>>2],d&3)+rank8[i], c = i>>13;
// edata[slot] = src | bf16(norm)<<16  (4B packed).
__global__ __launch_bounds__(256) void GCN_fill_k(const int* __restrict__ edge,
                                                  const uchar* __restrict__ rank8,
                                                  const uint* __restrict__ cw,
                                                  const int2* __restrict__ rd2,
                                                  uint* __restrict__ edata,
                                                  int E, int nWords) {
    int i = blockIdx.x * 256 + threadIdx.x;
    if (i >= E) return;
    int s = edge[i];
    int d = edge[E + i];
    int rk = (int)rank8[i];
    int c = i >> ECH_LOG;
    uint pw = cw[(size_t)c * nWords + (d >> 2)];
    int pfx = (int)((pw >> ((d & 3) << 3)) & 0xFFu);
    int2 rdd = rd2[d];
    float ds = __int_as_float(rd2[s].y);
    float nr = ds * __int_as_float(rdd.y);
    edata[rdd.x + 1 + pfx + rk] = (uint)s | ((uint)f2bf(nr) << 16);
}

// MEGA-B: agg1 (16 lanes/node, x8-deep gather MLP) -> h in LDS -> gemm2.
// edata packed 4B: src = lo16, norm = bf16 hi16. h2 written bf16.
__global__ __launch_bounds__(256) void GCN_agg1gemm2_k(
        const ushort* __restrict__ h1, const int2* __restrict__ rd2,
        const uint* __restrict__ ed, const float* __restrict__ b1,
        const float* __restrict__ W2, ushort* __restrict__ h2b, int N) {
    __shared__ float w2s[FH][FO];        // 8 KiB
    __shared__ float hs[16][FH + 4];     // 8.25 KiB
    int tid = threadIdx.x;
    #pragma unroll
    for (int j = 0; j < (FH * FO) / 256; j++) {
        int i = tid + j * 256;
        w2s[i >> 4][i & 15] = W2[i];
    }

    int node0 = blockIdx.x * 16;
    int local = tid >> 4;
    int j = tid & 15;             // 16B unit: cols 8j..8j+7
    int node = node0 + local;

    if (node < N) {
        int beg = rd2[node].x, end = rd2[node + 1].x;
        const uint4* hp = (const uint4*)h1;

        float a[8];
        #pragma unroll
        for (int t = 0; t < 8; t++) a[t] = 0.f;

        int i = beg;
        for (; i + 8 <= end; i += 8) {
            uint e[8];
            uint4 gg[8];
            #pragma unroll
            for (int t = 0; t < 8; t++) e[t] = ed[i + t];
            #pragma unroll
            for (int t = 0; t < 8; t++) gg[t] = hp[(size_t)(e[t] & 0xFFFFu) * 16 + j];
            #pragma unroll
            for (int t = 0; t < 8; t++) {
                float w = bf2f((ushort)(e[t] >> 16));
                #pragma unroll
                for (int q = 0; q < 4; q++) {
                    uint u = (&gg[t].x)[q];
                    a[q*2+0] += __uint_as_float(u << 16) * w;
                    a[q*2+1] += __uint_as_float(u & 0xFFFF0000u) * w;
                }
            }
        }
        for (; i < end; i++) {
            uint e = ed[i];
            float w = bf2f((ushort)(e >> 16));
            uint4 g = hp[(size_t)(e & 0xFFFFu) * 16 + j];
            #pragma unroll
            for (int q = 0; q < 4; q++) {
                uint u = (&g.x)[q];
                a[q*2+0] += __uint_as_float(u << 16) * w;
                a[q*2+1] += __uint_as_float(u & 0xFFFF0000u) * w;
            }
        }

        const float4* bp = (const float4*)b1;
        float4 bb0 = bp[j * 2 + 0];
        float4 bb1 = bp[j * 2 + 1];
        float4 o0, o1;
        o0.x = fmaxf(a[0] + bb0.x, 0.f);
        o0.y = fmaxf(a[1] + bb0.y, 0.f);
        o0.z = fmaxf(a[2] + bb0.z, 0.f);
        o0.w = fmaxf(a[3] + bb0.w, 0.f);
        o1.x = fmaxf(a[4] + bb1.x, 0.f);
        o1.y = fmaxf(a[5] + bb1.y, 0.f);
        o1.z = fmaxf(a[6] + bb1.z, 0.f);
        o1.w = fmaxf(a[7] + bb1.w, 0.f);
        *(float4*)&hs[local][j * 8 + 0] = o0;
        *(float4*)&hs[local][j * 8 + 4] = o1;
    }
    __syncthreads();

    float acc = 0.f;
    #pragma unroll 8
    for (int k = 0; k < FH; k++) acc += hs[local][k] * w2s[k][j];
    if (node < N) h2b[(size_t)node * FO + j] = f2bf(acc);
}

// AGG2 (bf16 h2, 4B edata) + bias + log_softmax. 8 lanes/node, x8 unroll.
__global__ __launch_bounds__(256) void GCN_agg2_k(const ushort* __restrict__ h2b,
                                                  const int2* __restrict__ rd2,
                                                  const uint* __restrict__ ed,
                                                  const float* __restrict__ b2,
                                                  float* __restrict__ out, int N) {
    int tid = threadIdx.x;
    int node = blockIdx.x * 32 + (tid >> 3);
    if (node >= N) return;
    int f2 = tid & 7;                        // cols 2*f2, 2*f2+1
    int beg = rd2[node].x, end = rd2[node + 1].x;
    const uint* hp = (const uint*)h2b;       // row = 8 uints (16 bf16)
    float a0 = 0.f, a1 = 0.f;
    int i = beg;
    for (; i + 8 <= end; i += 8) {
        uint e[8];
        uint u[8];
        #pragma unroll
        for (int t = 0; t < 8; t++) e[t] = ed[i + t];
        #pragma unroll
        for (int t = 0; t < 8; t++) u[t] = hp[(size_t)(e[t] & 0xFFFFu) * 8 + f2];
        #pragma unroll
        for (int t = 0; t < 8; t++) {
            float w = bf2f((ushort)(e[t] >> 16));
            a0 += __uint_as_float(u[t] << 16) * w;
            a1 += __uint_as_float(u[t] & 0xFFFF0000u) * w;
        }
    }
    for (; i < end; i++) {
        uint e = ed[i];
        uint u = hp[(size_t)(e & 0xFFFFu) * 8 + f2];
        float w = bf2f((ushort)(e >> 16));
        a0 += __uint_as_float(u << 16) * w;
        a1 += __uint_as_float(u & 0xFFFF0000u) * w;
    }
    float2 bb = ((const float2*)b2)[f2];
    float v0 = a0 + bb.x;
    float v1 = a1 + bb.y;
    float mx = fmaxf(v0, v1);
    #pragma unroll
    for (int m = 4; m >= 1; m >>= 1) mx = fmaxf(mx, __shfl_xor(mx, m, 8));
    float s = expf(v0 - mx) + expf(v1 - mx);
    #pragma unroll
    for (int m = 4; m >= 1; m >>= 1) s += __shfl_xor(s, m, 8);
    float ls = logf(s);
    float2 o = make_float2(v0 - mx - ls, v1 - mx - ls);
    ((float2*)out)[(size_t)node * 8 + f2] = o;
}

extern "C" void kernel_launch(void* const* d_in, const int* in_sizes, int n_in,
                              void* d_out, int out_size, void* d_ws, size_t ws_size,
                              hipStream_t stream) {
    (void)n_in; (void)out_size; (void)ws_size;
    const float* x  = (const float*)d_in[0];
    const int*   edp = (const int*)d_in[1];
    const float* W1 = (const float*)d_in[2];
    const float* b1 = (const float*)d_in[3];
    const float* W2 = (const float*)d_in[4];
    const float* b2 = (const float*)d_in[5];
    float* out = (float*)d_out;

    int N = in_sizes[0] / FIN;   // 50000
    int E = in_sizes[1] / 2;     // 800000
    int M = E + N;
    int nWords = (N + 3) / 4;                // 12500 (4 nodes/word)
    int wph = (nWords + 1) / 2;              // 6250 (<= WPH)
    int nScanBlocks = (N + 255) / 256;       // 196
    int nChpfx = (nWords + 63) / 64;         // 196

    char* p = (char*)d_ws;
    auto take = [&](size_t bytes) -> char* {
        char* r = p;
        p += (bytes + 255) & ~(size_t)255;
        return r;
    };
    int*    count  = (int*)take((size_t)N * 4);
    uchar*  rank8  = (uchar*)take((size_t)E);
    uint*   cw     = (uint*)take((size_t)NCHUNK * nWords * 4);   // 4.9 MB
    int2*   rd2    = (int2*)take((size_t)(N + 1) * 8);
    int*    bsum   = (int*)take((size_t)nChpfx * 4);
    uint*   edata  = (uint*)take((size_t)M * 4);
    ushort* h1     = (ushort*)take((size_t)N * FH * 2);
    ushort* h2b    = (ushort*)take((size_t)N * FO * 2);

    int eBlocks = (E + 255) / 256;            // 3125
    int nGemm   = (N + G1_BR - 1) / G1_BR;    // 782
    int nHist   = 2 * NCHUNK;                 // 196

    GCN_histgemm_k<<<nHist + nGemm, 256, 0, stream>>>(
        x, W1, h1, edp, cw, rank8, N, E, nHist, nWords, wph);
    GCN_chpfx_k<<<nChpfx, 256, 0, stream>>>(cw, count, bsum, N, nWords);
    GCN_scan2_k<<<nScanBlocks, 256, 0, stream>>>(count, bsum, rd2, edata, N);
    GCN_fill_k<<<eBlocks, 256, 0, stream>>>(edp, rank8, cw, rd2, edata, E, nWords);
    GCN_agg1gemm2_k<<<(N + 15) / 16, 256, 0, stream>>>(h1, rd2, edata, b1, W2, h2b, N);
    GCN_agg2_k<<<(N + 31) / 32, 256, 0, stream>>>(h2b, rd2, edata, b2, out, N);
}